// Round 6
// baseline (2047.674 us; speedup 1.0000x reference)
//
#include <hip/hip_runtime.h>
#include <hip/hip_bf16.h>
#include <cmath>

#define B_ 64
#define P_ 512
#define N_ 2048
#define E_ 128

__device__ __forceinline__ float nan2num(float x) {
  if (x != x) return 0.f;
  return fminf(fmaxf(x, -3.402823466e38f), 3.402823466e38f);
}

// 10*tanh(x), stable at +/-inf
__device__ __forceinline__ float tanh10(float x) {
  float e = __expf(2.f * x);
  return 10.f * (1.f - 2.f / (e + 1.f));
}

// ---------------- kernel 1: q = q1@Wq1 + q2@Wq2 + cat@Wq_last ; sigmoid ----------------
// 8 rows per block, 128 threads (thread = output e). W columns coalesced, rows via scalar loads.
__global__ __launch_bounds__(128) void k_qsig(
    const float* __restrict__ eln, const float* __restrict__ loadv,
    const float* __restrict__ leftv, const float* __restrict__ q1in,
    const float* __restrict__ q2in, const float* __restrict__ Wq1,
    const float* __restrict__ Wq2, const float* __restrict__ Wql,
    float* __restrict__ sigq)
{
  const int e = threadIdx.x;
  const int bp0 = blockIdx.x * 8;
  float acc[8];
#pragma unroll
  for (int r = 0; r < 8; ++r) acc[r] = 0.f;

  const float* __restrict__ r1 = q1in + (size_t)bp0 * E_;
#pragma unroll 4
  for (int i = 0; i < E_; ++i) {
    const float w = Wq1[i * E_ + e];
#pragma unroll
    for (int r = 0; r < 8; ++r) acc[r] = fmaf(r1[r * E_ + i], w, acc[r]);
  }
  const float* __restrict__ r2 = q2in + (size_t)bp0 * E_;
#pragma unroll 4
  for (int i = 0; i < E_; ++i) {
    const float w = Wq2[i * E_ + e];
#pragma unroll
    for (int r = 0; r < 8; ++r) acc[r] = fmaf(r2[r * E_ + i], w, acc[r]);
  }
  const float* __restrict__ r3 = eln + (size_t)bp0 * E_;
#pragma unroll 4
  for (int i = 0; i < E_; ++i) {
    const float w = Wql[i * E_ + e];
#pragma unroll
    for (int r = 0; r < 8; ++r) acc[r] = fmaf(r3[r * E_ + i], w, acc[r]);
  }
  const float wl0 = Wql[128 * E_ + e];
  const float wl1 = Wql[129 * E_ + e];
#pragma unroll
  for (int r = 0; r < 8; ++r) {
    float a = acc[r] + loadv[bp0 + r] * wl0 + leftv[bp0 + r] * wl1;
    sigq[(size_t)(bp0 + r) * E_ + e] = 1.f / (1.f + __expf(-a));
  }
}

// ---------------- kernel 2: e_k = exp(nodes@Wk), ekv = e_k * (nodes@Wv) ----------------
// 16 rows per block, 128 threads (thread = output e).
__global__ __launch_bounds__(128) void k_kv(
    const float* __restrict__ nodes, const float* __restrict__ Wk,
    const float* __restrict__ Wv, float* __restrict__ ekq,
    float* __restrict__ ekvq)
{
  const int e = threadIdx.x;
  const int r0 = blockIdx.x * 16;  // row index within B*N
  float ak[16], av[16];
#pragma unroll
  for (int r = 0; r < 16; ++r) { ak[r] = 0.f; av[r] = 0.f; }
  const float* __restrict__ nb = nodes + (size_t)r0 * E_;
#pragma unroll 4
  for (int i = 0; i < E_; ++i) {
    const float wk = Wk[i * E_ + e];
    const float wv = Wv[i * E_ + e];
#pragma unroll
    for (int r = 0; r < 16; ++r) {
      const float nv = nb[r * E_ + i];
      ak[r] = fmaf(nv, wk, ak[r]);
      av[r] = fmaf(nv, wv, av[r]);
    }
  }
#pragma unroll
  for (int r = 0; r < 16; ++r) {
    const float ekx = __expf(ak[r]);
    const size_t o = (size_t)(r0 + r) * E_ + e;
    ekq[o] = ekx;
    ekvq[o] = ekx * av[r];
  }
}

// ---------------- kernel 3: main fused AFT + score; writes clipped logits to out ----------------
// Block = 256 threads, tile = 64 p rows x all N. grid = B * (P/64) = 512.
// pass 1: numer/denom over N (ebias in LDS [p][72]); pass 2: score = aft @ nodes^T (nodesT staged in LDS).
__global__ __launch_bounds__(256, 2) void k_main(
    const float* __restrict__ dist, const float* __restrict__ ninf,
    const float* __restrict__ ekq, const float* __restrict__ ekvq,
    const float* __restrict__ nodes, const float* __restrict__ sigq,
    const float* __restrict__ ls, const float* __restrict__ aa,
    const float* __restrict__ pa, float* __restrict__ out)
{
  __shared__ float aft[E_ * 68];    // [e][p], row stride 68 (16B-aligned rows, bank-spread)
  __shared__ float pool[64 * 72];   // union: ebias [64 p][72] | nodesT [16 e][257 n] (4112 <= 4608)

  const int t = threadIdx.x;
  // XCD swizzle: 512 blocks, 8 XCDs -> same-b blocks share an XCD L2
  const int wid = (blockIdx.x & 7) * 64 + (blockIdx.x >> 3);
  const int b = wid >> 3;
  const int p0 = (wid & 7) * 64;

  const float ca = ls[0] * aa[0];
  const float cp = ls[0] * pa[0];

  const int ex = t & 127;  // e lane for pass 1
  const int pg = t >> 7;   // p half (0..1)

  const float* __restrict__ ekb  = ekq  + (size_t)b * N_ * E_;
  const float* __restrict__ ekvb = ekvq + (size_t)b * N_ * E_;

  float accN[32], accD[32];
#pragma unroll
  for (int p = 0; p < 32; ++p) { accN[p] = 0.f; accD[p] = 0.f; }

  // ---------------- pass 1: numer/denom ----------------
  for (int nt = 0; nt < N_ / 64; ++nt) {
    const int n0 = nt * 64;
    __syncthreads();
    // stage ebias tile [64 p][64 n] -> pool[p*72 + n]
#pragma unroll
    for (int rep = 0; rep < 4; ++rep) {
      const int id = t + rep * 256;      // 0..1023 float4s
      const int pl = id >> 4;
      const int n4 = (id & 15) * 4;
      const size_t g = (size_t)(b * P_ + p0 + pl) * N_ + n0 + n4;
      const float4 d4 = *(const float4*)(dist + g);
      const float4 m4 = *(const float4*)(ninf + g);
      float4 e4;
      e4.x = __expf(fmaf(-ca, d4.x, m4.x));
      e4.y = __expf(fmaf(-ca, d4.y, m4.y));
      e4.z = __expf(fmaf(-ca, d4.z, m4.z));
      e4.w = __expf(fmaf(-ca, d4.w, m4.w));
      *(float4*)(pool + pl * 72 + n4) = e4;
    }
    __syncthreads();
#pragma unroll 1
    for (int c = 0; c < 8; ++c) {        // 8 n per chunk
      float ekr[8], ekvr[8];
#pragma unroll
      for (int j = 0; j < 8; ++j) {
        const size_t gn = (size_t)(n0 + c * 8 + j) * E_ + ex;
        ekr[j]  = ekb[gn];
        ekvr[j] = ekvb[gn];
      }
#pragma unroll
      for (int p = 0; p < 32; ++p) {
        const float4 e0 = *(const float4*)(pool + (pg * 32 + p) * 72 + c * 8);
        const float4 e1 = *(const float4*)(pool + (pg * 32 + p) * 72 + c * 8 + 4);
        float eb[8] = {e0.x, e0.y, e0.z, e0.w, e1.x, e1.y, e1.z, e1.w};
#pragma unroll
        for (int j = 0; j < 8; ++j) {
          accN[p] = fmaf(eb[j], ekvr[j], accN[p]);
          accD[p] = fmaf(eb[j], ekr[j],  accD[p]);
        }
      }
    }
  }

  // ---------------- transition: aft = sigmoid_q * nan_to_num(numer)/(nan_to_num(denom)+1e-20)
  __syncthreads();
#pragma unroll
  for (int p = 0; p < 32; ++p) {
    const int pp = pg * 32 + p;
    const float w = nan2num(accN[p]) / (nan2num(accD[p]) + 1e-20f);
    const float sg = sigq[(size_t)(b * P_ + p0 + pp) * E_ + ex];
    aft[ex * 68 + pp] = sg * w;
  }
  // (barrier at top of first et iteration below covers the pool reuse)

  // ---------------- pass 2: score = aft @ nodes^T, logits -> out ----------------
  const int tn = t & 31;  // n lane
  const int tp = t >> 5;  // p group (0..7), 8 p each
  const float* __restrict__ nb = nodes + (size_t)b * N_ * E_;
  const float inv_sqrt_e = 0.088388347648318447f;  // 1/sqrt(128)

  for (int nt2 = 0; nt2 < 8; ++nt2) {
    const int n0 = nt2 * 256;
    float acc2[64];
#pragma unroll
    for (int i = 0; i < 64; ++i) acc2[i] = 0.f;

    for (int et = 0; et < 8; ++et) {     // 16 e per chunk
      __syncthreads();
      // stage nodesT [16 e][256 n] -> pool[e*257 + n]
#pragma unroll
      for (int rep = 0; rep < 4; ++rep) {
        const int id = t + rep * 256;    // 0..1023 float4s
        const int nl = id >> 2;          // 0..255
        const int e4 = (id & 3) * 4;     // 0..12
        const float4 v = *(const float4*)(nb + (size_t)(n0 + nl) * E_ + et * 16 + e4);
        pool[(e4 + 0) * 257 + nl] = v.x;
        pool[(e4 + 1) * 257 + nl] = v.y;
        pool[(e4 + 2) * 257 + nl] = v.z;
        pool[(e4 + 3) * 257 + nl] = v.w;
      }
      __syncthreads();
#pragma unroll 1
      for (int es = 0; es < 16; ++es) {
        const int eg = et * 16 + es;
        const float4 a0 = *(const float4*)(aft + eg * 68 + tp * 8);
        const float4 a1 = *(const float4*)(aft + eg * 68 + tp * 8 + 4);
        const float avv[8] = {a0.x, a0.y, a0.z, a0.w, a1.x, a1.y, a1.z, a1.w};
        float nv[8];
#pragma unroll
        for (int k = 0; k < 8; ++k) nv[k] = pool[es * 257 + tn + 32 * k];
#pragma unroll
        for (int pp = 0; pp < 8; ++pp)
#pragma unroll
          for (int k = 0; k < 8; ++k)
            acc2[pp * 8 + k] = fmaf(avv[pp], nv[k], acc2[pp * 8 + k]);
      }
    }
    // epilogue: logits = 10*tanh(score/sqrt(E) + cp*(-dist)) + ninf
#pragma unroll
    for (int pp = 0; pp < 8; ++pp) {
      const size_t gb = (size_t)(b * P_ + p0 + tp * 8 + pp) * N_ + n0 + tn;
#pragma unroll
      for (int k = 0; k < 8; ++k) {
        const float d  = dist[gb + 32 * k];
        const float mi = ninf[gb + 32 * k];
        const float sc = fmaf(acc2[pp * 8 + k], inv_sqrt_e, -cp * d);
        out[gb + 32 * k] = tanh10(sc) + mi;
      }
    }
  }
}

// ---------------- kernel 4: in-place row softmax over N ----------------
__global__ __launch_bounds__(256) void k_soft(float* __restrict__ out)
{
  __shared__ float red[8];
  const int t = threadIdx.x;
  float* __restrict__ r = out + (size_t)blockIdx.x * N_;
  float4 x0 = *(const float4*)(r + t * 4);
  float4 x1 = *(const float4*)(r + 1024 + t * 4);
  float m = fmaxf(fmaxf(fmaxf(x0.x, x0.y), fmaxf(x0.z, x0.w)),
                  fmaxf(fmaxf(x1.x, x1.y), fmaxf(x1.z, x1.w)));
#pragma unroll
  for (int off = 32; off >= 1; off >>= 1)
    m = fmaxf(m, __shfl_xor(m, off, 64));
  if ((t & 63) == 0) red[t >> 6] = m;
  __syncthreads();
  m = fmaxf(fmaxf(red[0], red[1]), fmaxf(red[2], red[3]));

  float e0 = __expf(x0.x - m), e1 = __expf(x0.y - m);
  float e2 = __expf(x0.z - m), e3 = __expf(x0.w - m);
  float e4 = __expf(x1.x - m), e5 = __expf(x1.y - m);
  float e6 = __expf(x1.z - m), e7 = __expf(x1.w - m);
  float s = ((e0 + e1) + (e2 + e3)) + ((e4 + e5) + (e6 + e7));
#pragma unroll
  for (int off = 32; off >= 1; off >>= 1)
    s += __shfl_xor(s, off, 64);
  if ((t & 63) == 0) red[4 + (t >> 6)] = s;
  __syncthreads();
  s = (red[4] + red[5]) + (red[6] + red[7]);
  const float inv = 1.f / s;
  x0.x = e0 * inv; x0.y = e1 * inv; x0.z = e2 * inv; x0.w = e3 * inv;
  x1.x = e4 * inv; x1.y = e5 * inv; x1.z = e6 * inv; x1.w = e7 * inv;
  *(float4*)(r + t * 4) = x0;
  *(float4*)(r + 1024 + t * 4) = x1;
}

extern "C" void kernel_launch(void* const* d_in, const int* in_sizes, int n_in,
                              void* d_out, int out_size, void* d_ws, size_t ws_size,
                              hipStream_t stream)
{
  const float* eln   = (const float*)d_in[0];
  const float* loadv = (const float*)d_in[1];
  const float* leftv = (const float*)d_in[2];
  const float* dist  = (const float*)d_in[3];
  const float* ls    = (const float*)d_in[4];
  const float* ninf  = (const float*)d_in[5];
  const float* nodes = (const float*)d_in[6];
  const float* q1    = (const float*)d_in[7];
  const float* q2    = (const float*)d_in[8];
  const float* Wq1   = (const float*)d_in[9];
  const float* Wq2   = (const float*)d_in[10];
  const float* Wql   = (const float*)d_in[11];
  const float* Wk    = (const float*)d_in[12];
  const float* Wv    = (const float*)d_in[13];
  const float* aa    = (const float*)d_in[14];
  const float* pa    = (const float*)d_in[15];
  float* out = (float*)d_out;

  // workspace layout (floats): sigq [B*P*E] | e_k [B*N*E] | ekv [B*N*E]  (~151 MB)
  float* sigq = (float*)d_ws;
  float* ekq  = sigq + (size_t)B_ * P_ * E_;
  float* ekvq = ekq + (size_t)B_ * N_ * E_;

  k_qsig<<<dim3(B_ * P_ / 8), dim3(128), 0, stream>>>(eln, loadv, leftv, q1, q2,
                                                      Wq1, Wq2, Wql, sigq);
  k_kv<<<dim3(B_ * N_ / 16), dim3(128), 0, stream>>>(nodes, Wk, Wv, ekq, ekvq);
  k_main<<<dim3(512), dim3(256), 0, stream>>>(dist, ninf, ekq, ekvq, nodes, sigq,
                                              ls, aa, pa, out);
  k_soft<<<dim3(B_ * P_), dim3(256), 0, stream>>>(out);
}